// Round 8
// baseline (60.747 us; speedup 1.0000x reference)
//
#include <hip/hip_runtime.h>
#include <hip/hip_bf16.h>

#define SCALE (1.0f/16.0f)

typedef __attribute__((ext_vector_type(8))) short short8;
typedef __attribute__((ext_vector_type(4))) short short4v;
typedef __attribute__((ext_vector_type(2))) float f32x2;
typedef __attribute__((ext_vector_type(4))) float f32x4;
typedef __attribute__((ext_vector_type(16))) float f32x16;
typedef unsigned int u32;

__device__ __forceinline__ u32 pk2bf(f32x2 v) {
    __hip_bfloat16 h0 = __float2bfloat16(v[0]);
    __hip_bfloat16 h1 = __float2bfloat16(v[1]);
    return (u32)*(unsigned short*)&h0 | ((u32)*(unsigned short*)&h1 << 16);
}

// ---------------- K0: feat f32 [256][4096] -> bf16 (same layout, c-major) ----------------
__global__ void k_prep(const float* __restrict__ f, __hip_bfloat16* __restrict__ o) {
    int i = blockIdx.x * 256 + threadIdx.x;   // 1024 blocks -> 262144 f32x4 groups
    f32x4 v = ((const f32x4*)f)[i];
    short4v p;
#pragma unroll
    for (int u = 0; u < 4; ++u) {
        __hip_bfloat16 h = __float2bfloat16(v[u]); p[u] = *(short*)&h;
    }
    ((short4v*)o)[i] = p;
}

// ---------------- K2: permute W -> 32x32x16 MFMA A-fragment order ----------------
// chunk ch = ((j*8 + ot)*16 + sk)*64 + l : 8 bf16 of W[o = ot*32 + (l&31)][k = j*256 + sk*16 + (l>>5)*8 + i]
__global__ void k_permw(const float* __restrict__ wf, __hip_bfloat16* __restrict__ wr) {
    int ch = blockIdx.x * 256 + threadIdx.x;   // 65536 chunks
    int l  = ch & 63;
    int sk = (ch >> 6) & 15;
    int ot = (ch >> 10) & 7;
    int j  = ch >> 13;
    int o = ot*32 + (l & 31);
    int k = j*256 + sk*16 + (l >> 5)*8;
    const float* src = wf + (size_t)o*2048 + k;
    f32x4 a = *(const f32x4*)src;
    f32x4 b = *(const f32x4*)(src + 4);
    short8 p;
#pragma unroll
    for (int u = 0; u < 4; ++u) {
        __hip_bfloat16 h = __float2bfloat16(a[u]); p[u] = *(short*)&h;
    }
#pragma unroll
    for (int u = 0; u < 4; ++u) {
        __hip_bfloat16 h = __float2bfloat16(b[u]); p[4+u] = *(short*)&h;
    }
    *((short8*)wr + ch) = p;
}

// ---------------- K3: fused all-MFMA ROIAlign + GEMM ----------------
// Grid 256 = (n 0..127) x (hw-half). Block 1024 = 16 waves = 8 o-tiles x 2 k-halves.
// Per box j: Tbuild (64pix x 32hw interp matrix, bf16, LDS) -> stage1 MFMA
// (featpatch x T -> Pl[32hw][256c]) -> stage2 MFMA (W x Pl). 3-deep pipeline, 1 barrier/j.
__global__ void __launch_bounds__(1024, 4) k_fused(
    const __hip_bfloat16* __restrict__ featb,
    const float* __restrict__ boxes,
    const __hip_bfloat16* __restrict__ wr,
    const float* __restrict__ bfuse,
    float* __restrict__ out)
{
    __shared__ char Pl[2][16384];     // [32 hw][256 c] bf16, XOR-swizzled
    __shared__ char Tl[2][4096];      // [32 hw][64 pix] bf16, XOR-swizzled
    __shared__ float red[8*64*16];    // split-K reduce (32 KB)

    int tid = threadIdx.x;
    int lane = tid & 63, wid = tid >> 6;
    int r31 = lane & 31, l5 = lane >> 5;
    int ot = wid & 7, kh = wid >> 3;
    int bid = blockIdx.x;
    int n = bid & 127, hwt = bid >> 7;      // partners (n, hwt) share bid%8 -> same XCD

    int nb_base = (n & 15) * 8;
    int off = n >> 4;
    int t3 = off + (off >= 4 ? 1 : 0);
    int ci = t3 / 3, cj = t3 - ci*3;

    int key = (r31 & 7) << 4;

    // per-box uniform params
    struct BoxP { float orgx, stepx, orgy, stepy; int xb, yb; };
    auto boxparams = [&](int jj) {
        int nbx = nb_base + jj;
        float x1 = boxes[nbx*4+0], y1 = boxes[nbx*4+1];
        float x2 = boxes[nbx*4+2], y2 = boxes[nbx*4+3];
        float w3 = (x2-x1)*(1.f/3.f), h3 = (y2-y1)*(1.f/3.f);
        BoxP b;
        b.orgx = (x1 + cj*w3)*SCALE - 0.5f;
        b.orgy = (y1 + ci*h3)*SCALE - 0.5f;
        b.stepx = w3*(SCALE*(1.f/14.f));
        b.stepy = h3*(SCALE*(1.f/14.f));
        float p0 = fminf(fmaxf(b.orgx + 0.5f*b.stepx, 0.f), 63.f);
        b.xb = min((int)fminf(floorf(p0), 62.f), 56);
        p0 = fminf(fmaxf(b.orgy + 0.5f*b.stepy, 0.f), 63.f);
        b.yb = min((int)fminf(floorf(p0), 62.f), 56);
        return b;
    };

    // ---- Tbuild: threads 512..767 build Tl[buf] (32 rows x 64 pix) for box jj ----
    auto tbuild = [&](int jj, int buf) {
        if (tid >= 512 && tid < 768) {
            int tid2 = tid - 512;
            int row = tid2 >> 3, py = tid2 & 7;
            char* T = Tl[buf] + row*128;
            int k2 = (row & 7) << 4;
            int g = hwt*32 + row;
            u32 o4[4] = {0u,0u,0u,0u};
            if (g <= 48) {
                BoxP bp = boxparams(jj);
                int h = (g*37) >> 8, w = g - h*7;
                // x 3-tap
                float pa = fminf(fmaxf(bp.orgx + (2*w + 0.5f)*bp.stepx, 0.f), 63.f);
                float fla = fminf(floorf(pa), 62.f);
                float pb = fminf(fmaxf(bp.orgx + (2*w + 1.5f)*bp.stepx, 0.f), 63.f);
                float flb = fminf(floorf(pb), 62.f);
                float fa = pa - fla, fb = pb - flb, d = flb - fla;
                int px0 = (int)fla - bp.xb;
                float b0 = (1.f-fa) + (1.f-d)*(1.f-fb);
                float b1 = fa + (1.f-d)*fb + d*(1.f-fb);
                float b2 = d*fb;
                // y 3-tap (0.25 avg folded)
                pa = fminf(fmaxf(bp.orgy + (2*h + 0.5f)*bp.stepy, 0.f), 63.f);
                fla = fminf(floorf(pa), 62.f);
                pb = fminf(fmaxf(bp.orgy + (2*h + 1.5f)*bp.stepy, 0.f), 63.f);
                flb = fminf(floorf(pb), 62.f);
                fa = pa - fla; fb = pb - flb; d = flb - fla;
                int py0 = (int)fla - bp.yb;
                float a0 = 0.25f*((1.f-fa) + (1.f-d)*(1.f-fb));
                float a1 = 0.25f*(fa + (1.f-d)*fb + d*(1.f-fb));
                float a2 = 0.25f*(d*fb);
                int dy = py - py0;
                float ys = (dy==0)?a0 : (dy==1)?a1 : (dy==2)?a2 : 0.f;
#pragma unroll
                for (int q = 0; q < 4; ++q) {
                    f32x2 v;
#pragma unroll
                    for (int s = 0; s < 2; ++s) {
                        int dx = q*2 + s - px0;
                        float xs = (dx==0)?b0 : (dx==1)?b1 : (dx==2)?b2 : 0.f;
                        v[s] = ys * xs;
                    }
                    o4[q] = pk2bf(v);
                }
            }
#pragma unroll
            for (int q = 0; q < 4; ++q)
                *(u32*)(T + ((py*16 + q*4) ^ k2)) = o4[q];
        }
    };

    // ---- stage1: waves 0..7, pool box jj via MFMA -> Pl[buf] ----
    auto stage1 = [&](int jj, int buf) {
        if (wid < 8) {
            BoxP bp = boxparams(jj);
            const __hip_bfloat16* fb = featb + (size_t)(wid*32 + r31)*4096 + bp.yb*64 + bp.xb;
            f32x16 a1;
#pragma unroll
            for (int i = 0; i < 16; ++i) a1[i] = 0.f;
#pragma unroll
            for (int s = 0; s < 4; ++s) {
                short8 af = *(const short8*)(fb + (2*s + l5)*64);
                short8 tf = *(const short8*)(Tl[buf] + r31*128 + ((s*32 + l5*16) ^ key));
                a1 = __builtin_amdgcn_mfma_f32_32x32x16_bf16(af, tf, a1, 0, 0, 0);
            }
            char* pd = Pl[buf] + r31*512;
#pragma unroll
            for (int r = 0; r < 8; ++r) {
                f32x2 v; v[0] = a1[2*r]; v[1] = a1[2*r+1];
                int cb2 = wid*64 + 4*(r&1) + 16*(r>>1) + 8*l5;
                *(u32*)(pd + (cb2 ^ key)) = pk2bf(v);
            }
        }
    };

    // ---- W prefetch (regs) + stage2 ----
    short8 Wf[2][8];
    auto prefW = [&](int buf, int j) {
        const short8* wb = (const short8*)wr + ((size_t)((j*8 + ot)*16 + kh*8)*64) + lane;
#pragma unroll
        for (int sk = 0; sk < 8; ++sk) Wf[buf][sk] = wb[sk*64];
    };

    f32x16 acc2;
#pragma unroll
    for (int i = 0; i < 16; ++i) acc2[i] = 0.f;

    prefW(0, 0);
    tbuild(0, 0);
    __syncthreads();
    stage1(0, 0);
    tbuild(1, 1);
    prefW(1, 1);
    __syncthreads();

#pragma unroll
    for (int j = 0; j < 8; ++j) {
        if (j < 7) stage1(j+1, (j+1)&1);
        if (j < 6) tbuild(j+2, j&1);
        {   // stage2(j): consume Wf[j&1] x Pl[j&1]
#pragma unroll
            for (int sk = 0; sk < 8; ++sk) {
                short8 pf = *(const short8*)(Pl[j&1] + r31*512 + ((((kh*8+sk)*32) + l5*16) ^ key));
                acc2 = __builtin_amdgcn_mfma_f32_32x32x16_bf16(Wf[j&1][sk], pf, acc2, 0, 0, 0);
            }
        }
        if (j < 6) prefW(j&1, j+2);
        __syncthreads();
    }

    // ---- split-K reduce + epilogue ----
    if (kh == 1) {
        float* rb = red + (size_t)(ot*64 + lane)*16;
#pragma unroll
        for (int q4 = 0; q4 < 4; ++q4) {
            f32x4 t;
#pragma unroll
            for (int i = 0; i < 4; ++i) t[i] = acc2[q4*4 + i];
            *(f32x4*)(rb + q4*4) = t;
        }
    }
    __syncthreads();
    if (kh == 0) {
        const float* rb = red + (size_t)(ot*64 + lane)*16;
        int hw = hwt*32 + r31;
        if (hw < 49) {
            float* ob = out + ((size_t)n*256)*49 + hw;
#pragma unroll
            for (int reg = 0; reg < 16; ++reg) {
                int o = ot*32 + (reg & 3) + 8*(reg >> 2) + 4*l5;
                float v = acc2[reg] + rb[reg] + bfuse[o];
                ob[(size_t)o*49] = fmaxf(v, 0.f);
            }
        }
    }
}

extern "C" void kernel_launch(void* const* d_in, const int* in_sizes, int n_in,
                              void* d_out, int out_size, void* d_ws, size_t ws_size,
                              hipStream_t stream) {
    const float* feat  = (const float*)d_in[0];   // [256,64,64]
    const float* boxes = (const float*)d_in[1];   // [128,4]
    const float* wf    = (const float*)d_in[2];   // [256,2048]
    const float* bfuse = (const float*)d_in[3];   // [256]
    float* out = (float*)d_out;                   // [128,256,7,7]

    char* ws = (char*)d_ws;
    __hip_bfloat16* wr    = (__hip_bfloat16*)ws;                 // 1 MB (permuted W)
    __hip_bfloat16* featb = (__hip_bfloat16*)(ws + (1u<<20));    // 2 MB (bf16 feat, c-major)

    k_prep<<<1024, 256, 0, stream>>>(feat, featb);
    k_permw<<<256, 256, 0, stream>>>(wf, wr);
    k_fused<<<256, 1024, 0, stream>>>(featb, boxes, wr, bfuse, out);
}

// Round 9
// 55.111 us; speedup vs baseline: 1.1023x; 1.1023x over previous
//
#include <hip/hip_runtime.h>
#include <hip/hip_bf16.h>

#define SCALE (1.0f/16.0f)

typedef __attribute__((ext_vector_type(8))) short short8;
typedef __attribute__((ext_vector_type(4))) short short4v;
typedef __attribute__((ext_vector_type(2))) float f32x2;
typedef __attribute__((ext_vector_type(4))) float f32x4;
typedef __attribute__((ext_vector_type(16))) float f32x16;
typedef __attribute__((ext_vector_type(2))) unsigned int u32x2;
typedef unsigned int u32;

__device__ __forceinline__ f32x2 unpk(u32 u) {
    f32x2 r;
    r[0] = __uint_as_float(u << 16);
    r[1] = __uint_as_float(u & 0xffff0000u);
    return r;
}
__device__ __forceinline__ u32 pk2bf(f32x2 v) {
    __hip_bfloat16 h0 = __float2bfloat16(v[0]);
    __hip_bfloat16 h1 = __float2bfloat16(v[1]);
    return (u32)*(unsigned short*)&h0 | ((u32)*(unsigned short*)&h1 << 16);
}

// ---------------- K1: transpose features f32 [256][4096] -> bf16 [4096 pix][256 c] ----------------
__global__ void k_transpose(const float* __restrict__ feat, __hip_bfloat16* __restrict__ featT) {
    __shared__ float t[64][65];
    int cb = (blockIdx.x >> 6) << 6;
    int pb = (blockIdx.x & 63) << 6;
    int lx = threadIdx.x & 63, ly = threadIdx.x >> 6;
#pragma unroll
    for (int i = 0; i < 16; ++i) {
        int cl = i*4 + ly;
        t[cl][lx] = feat[(size_t)(cb + cl) * 4096 + pb + lx];
    }
    __syncthreads();
#pragma unroll
    for (int i = 0; i < 16; ++i) {
        int pl = i*4 + ly;
        featT[(size_t)(pb + pl) * 256 + cb + lx] = __float2bfloat16(t[lx][pl]);
    }
}

// ---------------- K2: permute W -> 32x32x16 MFMA A-fragment order ----------------
// chunk ch = ((j*8 + ot)*16 + sk)*64 + l : 8 bf16 of W[o = ot*32 + (l&31)][k = j*256 + sk*16 + (l>>5)*8 + i]
__global__ void k_permw(const float* __restrict__ wf, __hip_bfloat16* __restrict__ wr) {
    int ch = blockIdx.x * 256 + threadIdx.x;   // 65536 chunks
    int l  = ch & 63;
    int sk = (ch >> 6) & 15;
    int ot = (ch >> 10) & 7;
    int j  = ch >> 13;
    int o = ot*32 + (l & 31);
    int k = j*256 + sk*16 + (l >> 5)*8;
    const float* src = wf + (size_t)o*2048 + k;
    f32x4 a = *(const f32x4*)src;
    f32x4 b = *(const f32x4*)(src + 4);
    short8 p;
#pragma unroll
    for (int u = 0; u < 4; ++u) {
        __hip_bfloat16 h = __float2bfloat16(a[u]); p[u] = *(short*)&h;
    }
#pragma unroll
    for (int u = 0; u < 4; ++u) {
        __hip_bfloat16 h = __float2bfloat16(b[u]); p[4+u] = *(short*)&h;
    }
    *((short8*)wr + ch) = p;
}

// ---------------- K3: fused ROIAlign + GEMM, 4 small blocks per CU ----------------
// Grid 512: bid -> (n = bid&127, oh = (bid>>7)&1, hh = bid>>8). 256 thr = 4 waves.
// Per j: {tables(j+2) ; pool(j+1) -> Pl[^] ; gemm(j) from Pl} one barrier.
// Wave = 32o x 32hw via MFMA 32x32x16. No split-K, no partials.
__global__ void __launch_bounds__(256, 4) k_fused(
    const __hip_bfloat16* __restrict__ featT,
    const float* __restrict__ boxes,
    const __hip_bfloat16* __restrict__ wr,
    const float* __restrict__ bfuse,
    float* __restrict__ out)
{
    __shared__ char Pl[2][16384];          // [32 hw][512 B] bf16, XOR-swizzled
    __shared__ f32x4 tabs[2][2][7];        // [j-buf][x/y][idx] = {pos0(abs), a0, a1, a2}

    int tid = threadIdx.x;
    int lane = tid & 63, wid = tid >> 6;   // 4 waves
    int r31 = lane & 31, l5 = lane >> 5;
    int bid = blockIdx.x;
    int n  = bid & 127;
    int oh = (bid >> 7) & 1;
    int hh = bid >> 8;
    int HWn = hh ? 17 : 32;

    int nb_base = (n & 15) * 8;
    int off = n >> 4;
    int t3 = off + (off >= 4 ? 1 : 0);
    int ci = t3 / 3, cj = t3 - ci*3;

    f32x16 acc;
#pragma unroll
    for (int i = 0; i < 16; ++i) acc[i] = 0.f;

    // ---- 3-tap separable tables for box jj (waves 2,3) ----
    auto tables = [&](int jj) {
        if (wid == 2 || wid == 3) {
            int isy = wid - 2;
            int nbx = nb_base + jj;
            float bx1 = boxes[nbx*4+0], by1 = boxes[nbx*4+1];
            float bx2 = boxes[nbx*4+2], by2 = boxes[nbx*4+3];
            float w3 = (bx2-bx1)*(1.f/3.f), h3 = (by2-by1)*(1.f/3.f);
            float org  = isy ? (by1 + ci*h3)*SCALE - 0.5f : (bx1 + cj*w3)*SCALE - 0.5f;
            float step = (isy ? h3 : w3) * (SCALE*(1.f/14.f));   // half-bin
            float sc = isy ? 0.25f : 1.f;
            float p = org + ((float)lane + 0.5f)*step;
            float pc = fminf(fmaxf(p, 0.f), 63.f);
            float fl = fminf(floorf(pc), 62.f);
            float fr = pc - fl;
            float c0 = __shfl(fl, 2*lane);
            float c1 = __shfl(fl, 2*lane+1);
            float f  = __shfl(fr, 2*lane);
            float f2 = __shfl(fr, 2*lane+1);
            float d = c1 - c0;             // 0 or 1
            float a0 = sc*((1.f-f) + (1.f-d)*(1.f-f2));
            float a1 = sc*(f + (1.f-d)*f2 + d*(1.f-f2));
            float a2 = sc*(d*f2);
            if (lane < 7) {
                f32x4 e; e[0] = c0; e[1] = a0; e[2] = a1; e[3] = a2;
                tabs[jj & 1][isy][lane] = e;
            }
        }
    };

    // ---- pool box jj (9-tap separable, c-quad granularity) -> Pl[jj&1] ----
    auto pool = [&](int jj) {
        int buf = jj & 1;
        int cq = tid & 63, e0 = tid >> 6;
        const u32* fp = (const u32*)featT;   // pair units: pix*128 + cq*2
        for (int e = e0; e < HWn; e += 4) {
            int g = hh*32 + e;
            int h = (g*37) >> 8, w = g - h*7;
            f32x4 tx = tabs[buf][0][w], ty = tabs[buf][1][h];
            int x0 = (int)tx[0], y0 = (int)ty[0];
            int x2 = min(x0+2, 63), y2 = min(y0+2, 63);
            int r0 = (y0*64 + x0)*128 + cq*2;
            int r1 = r0 + 8192;
            int r2 = (y2*64 + x0)*128 + cq*2;
            int dx2 = (x2 - x0)*128;
            u32x2 F00 = *(const u32x2*)(fp + r0);
            u32x2 F01 = *(const u32x2*)(fp + r0 + 128);
            u32x2 F02 = *(const u32x2*)(fp + r0 + dx2);
            u32x2 F10 = *(const u32x2*)(fp + r1);
            u32x2 F11 = *(const u32x2*)(fp + r1 + 128);
            u32x2 F12 = *(const u32x2*)(fp + r1 + dx2);
            u32x2 F20 = *(const u32x2*)(fp + r2);
            u32x2 F21 = *(const u32x2*)(fp + r2 + 128);
            u32x2 F22 = *(const u32x2*)(fp + r2 + dx2);
            u32x2 res;
#pragma unroll
            for (int s = 0; s < 2; ++s) {
                f32x2 row0 = tx[1]*unpk(F00[s]) + tx[2]*unpk(F01[s]) + tx[3]*unpk(F02[s]);
                f32x2 row1 = tx[1]*unpk(F10[s]) + tx[2]*unpk(F11[s]) + tx[3]*unpk(F12[s]);
                f32x2 row2 = tx[1]*unpk(F20[s]) + tx[2]*unpk(F21[s]) + tx[3]*unpk(F22[s]);
                f32x2 v = ty[1]*row0 + ty[2]*row1 + ty[3]*row2;   // 0.25 folded into ty
                res[s] = pk2bf(v);
            }
            *(u32x2*)(Pl[buf] + e*512 + ((cq*8) ^ ((e & 7) << 4))) = res;
        }
    };

    // ---- GEMM step j: acc += W(j, ot) x Pl[j&1] ----
    auto gemm = [&](int j) {
        int buf = j & 1;
        int ot = oh*4 + wid;
        const short8* wb = (const short8*)wr + (size_t)((j*8 + ot)*16)*64 + lane;
#pragma unroll
        for (int sk = 0; sk < 16; ++sk) {
            short8 wfrag = wb[sk*64];
            int byo = r31*512 + ((sk*32 + l5*16) ^ ((r31 & 7) << 4));
            short8 pf = *(const short8*)(Pl[buf] + byo);
            acc = __builtin_amdgcn_mfma_f32_32x32x16_bf16(wfrag, pf, acc, 0, 0, 0);
        }
    };

    tables(0);
    __syncthreads();
    tables(1);
    pool(0);
    __syncthreads();
#pragma unroll
    for (int j = 0; j < 8; ++j) {
        if (j < 6) tables(j+2);
        if (j < 7) pool(j+1);
        gemm(j);
        if (j < 7) __syncthreads();
    }

    // ---- epilogue: bias + relu ----
    int hw = hh*32 + r31;
    if (hw < 49) {
        int ot = oh*4 + wid;
        float* ob = out + (size_t)n*12544 + hw;
#pragma unroll
        for (int reg = 0; reg < 16; ++reg) {
            int o = ot*32 + (reg & 3) + 8*(reg >> 2) + 4*l5;
            float v = acc[reg] + bfuse[o];
            ob[(size_t)o*49] = fmaxf(v, 0.f);
        }
    }
}

extern "C" void kernel_launch(void* const* d_in, const int* in_sizes, int n_in,
                              void* d_out, int out_size, void* d_ws, size_t ws_size,
                              hipStream_t stream) {
    const float* feat  = (const float*)d_in[0];   // [256,64,64]
    const float* boxes = (const float*)d_in[1];   // [128,4]
    const float* wf    = (const float*)d_in[2];   // [256,2048]
    const float* bfuse = (const float*)d_in[3];   // [256]
    float* out = (float*)d_out;                   // [128,256,7,7]

    char* ws = (char*)d_ws;
    __hip_bfloat16* wr    = (__hip_bfloat16*)ws;                 // 1 MB (permuted W)
    __hip_bfloat16* featT = (__hip_bfloat16*)(ws + (1u<<20));    // 2 MB

    k_transpose<<<256, 256, 0, stream>>>(feat, featT);
    k_permw<<<256, 256, 0, stream>>>(wf, wr);
    k_fused<<<512, 256, 0, stream>>>(featT, boxes, wr, bfuse, out);
}

// Round 10
// 47.168 us; speedup vs baseline: 1.2879x; 1.1684x over previous
//
#include <hip/hip_runtime.h>
#include <hip/hip_fp16.h>

#define SCALE (1.0f/16.0f)

typedef __attribute__((ext_vector_type(8))) _Float16 f16x8;
typedef __attribute__((ext_vector_type(4))) float f32x4;
typedef __attribute__((ext_vector_type(16))) float f32x16;
typedef __attribute__((ext_vector_type(2))) unsigned int u32x2;
typedef unsigned int u32;

__device__ __forceinline__ void gload16(const void* g, void* l) {
    __builtin_amdgcn_global_load_lds(
        (const __attribute__((address_space(1))) unsigned int*)g,
        (__attribute__((address_space(3))) unsigned int*)l, 16, 0, 0);
}
__device__ __forceinline__ __half2 asH2(u32 v) {
    union { u32 i; __half2 h; } u; u.i = v; return u.h;
}
__device__ __forceinline__ u32 asU32(__half2 h) {
    union { __half2 h; u32 i; } u; u.h = h; return u.i;
}
__device__ __forceinline__ int dupH2(float f) {
    __half h = __float2half_rn(f);
    __half2 d; d.x = h; d.y = h;
    union { __half2 h2; int i; } u; u.h2 = d; return u.i;
}

// ---------------- K1: transpose features f32 [256][4096] -> fp16 [4096 pix][256 c] ----------------
__global__ void k_transpose(const float* __restrict__ feat, __half* __restrict__ featT) {
    __shared__ float t[64][65];
    int cb = (blockIdx.x >> 6) << 6;
    int pb = (blockIdx.x & 63) << 6;
    int lx = threadIdx.x & 63, ly = threadIdx.x >> 6;
#pragma unroll
    for (int i = 0; i < 16; ++i) {
        int cl = i*4 + ly;
        t[cl][lx] = feat[(size_t)(cb + cl) * 4096 + pb + lx];
    }
    __syncthreads();
#pragma unroll
    for (int i = 0; i < 16; ++i) {
        int pl = i*4 + ly;
        featT[(size_t)(pb + pl) * 256 + cb + lx] = __float2half_rn(t[lx][pl]);
    }
}

// ---------------- K2: permute W -> 32x32x16 MFMA A-fragment order (fp16) ----------------
// chunk ch = ((j*8 + ot)*16 + sk)*64 + l : 8 fp16 of W[o = ot*32 + (l&31)][k = j*256 + sk*16 + (l>>5)*8 + i]
__global__ void k_permw(const float* __restrict__ wf, __half* __restrict__ wr) {
    int ch = blockIdx.x * 256 + threadIdx.x;   // 65536 chunks
    int l  = ch & 63;
    int sk = (ch >> 6) & 15;
    int ot = (ch >> 10) & 7;
    int j  = ch >> 13;
    int o = ot*32 + (l & 31);
    int k = j*256 + sk*16 + (l >> 5)*8;
    const float* src = wf + (size_t)o*2048 + k;
    f32x4 a = *(const f32x4*)src;
    f32x4 b = *(const f32x4*)(src + 4);
    f16x8 p;
#pragma unroll
    for (int u = 0; u < 4; ++u) p[u] = (_Float16)a[u];
#pragma unroll
    for (int u = 0; u < 4; ++u) p[4+u] = (_Float16)b[u];
    *((f16x8*)wr + ch) = p;
}

// ---------------- K3: fused ROIAlign + GEMM, LDS patch + fp16 pk-FIR ----------------
// Grid 512: (n 0..127, oh 0..1, hh 0..1). 256 thr = 4 waves (each 32o x 32hw).
// Per j: A:{gemm(j) || gload patch(j+1)} bar B:{pool(j+1) || tables(j+2)} bar.
__global__ void __launch_bounds__(256, 2) k_fused(
    const __half* __restrict__ featT,
    const float* __restrict__ boxes,
    const __half* __restrict__ wr,
    const float* __restrict__ bfuse,
    float* __restrict__ out)
{
    __shared__ char patch[32768];        // [y 8][px 8][c 256] fp16
    __shared__ char Pl[2][16384];        // [32 hw][256 c] fp16, XOR-swizzled
    __shared__ int4 tabs[2][2][7];       // [buf][x/y][idx] = {p0_local, a0h2, a1h2, a2h2}
    __shared__ int  pbs[2][2];           // [buf][xb, yb]

    int tid = threadIdx.x;
    int lane = tid & 63, wid = tid >> 6;
    int r31 = lane & 31, l5 = lane >> 5;
    int bid = blockIdx.x;
    int n  = bid & 127;
    int oh = (bid >> 7) & 1;
    int hh = bid >> 8;
    int HWn = hh ? 17 : 32;

    int nb_base = (n & 15) * 8;
    int off = n >> 4;
    int t3 = off + (off >= 4 ? 1 : 0);
    int ci = t3 / 3, cj = t3 - ci*3;

    f32x16 acc;
#pragma unroll
    for (int i = 0; i < 16; ++i) acc[i] = 0.f;

    // ---- 3-tap separable tables + patch base for box jj (waves 0,1) ----
    auto tables = [&](int jj) {
        if (wid < 2) {
            int isy = wid;
            int nbx = nb_base + jj;
            float bx1 = boxes[nbx*4+0], by1 = boxes[nbx*4+1];
            float bx2 = boxes[nbx*4+2], by2 = boxes[nbx*4+3];
            float w3 = (bx2-bx1)*(1.f/3.f), h3 = (by2-by1)*(1.f/3.f);
            float org  = isy ? (by1 + ci*h3)*SCALE - 0.5f : (bx1 + cj*w3)*SCALE - 0.5f;
            float step = (isy ? h3 : w3) * (SCALE*(1.f/14.f));   // half-bin
            float sc = isy ? 0.25f : 1.f;
            float p = org + ((float)lane + 0.5f)*step;
            float pc = fminf(fmaxf(p, 0.f), 63.f);
            float fl = fminf(floorf(pc), 62.f);
            float fr = pc - fl;
            float c0 = __shfl(fl, 2*lane);
            float c1 = __shfl(fl, 2*lane+1);
            float f  = __shfl(fr, 2*lane);
            float f2 = __shfl(fr, 2*lane+1);
            float fl0 = __shfl(fl, 0);
            int base = min((int)fl0, 56);
            float d = c1 - c0;             // 0 or 1
            float a0 = sc*((1.f-f) + (1.f-d)*(1.f-f2));
            float a1 = sc*(f + (1.f-d)*f2 + d*(1.f-f2));
            float a2 = sc*(d*f2);
            if (lane < 7) {
                int4 e;
                e.x = (int)c0 - base;
                e.y = dupH2(a0); e.z = dupH2(a1); e.w = dupH2(a2);
                tabs[jj & 1][isy][lane] = e;
            }
            if (lane == 0) pbs[jj & 1][isy] = base;
        }
    };

    // ---- stage 8x8 pixel patch of box jj into LDS (coalesced gload16) ----
    auto patchStage = [&](int jj) {
        int xb = pbs[jj & 1][0], yb = pbs[jj & 1][1];
#pragma unroll
        for (int it = 0; it < 8; ++it) {
            const __half* src = featT + ((size_t)((yb + it)*64 + xb))*256 + (size_t)(wid*64 + lane)*8;
            gload16(src, patch + it*4096 + wid*1024);
        }
    };

    // ---- pool box jj from LDS patch (fp16 packed 9-tap separable) -> Pl[jj&1] ----
    auto pool = [&](int jj) {
        int buf = jj & 1;
        int cq = tid & 63, e0 = tid >> 6;
        const char* pb = patch + cq*8;
        for (int e = e0; e < HWn; e += 4) {
            int g = hh*32 + e;
            int h = (g*37) >> 8, w = g - h*7;
            int4 tx = tabs[buf][0][w], ty = tabs[buf][1][h];
            int px0 = tx.x, py0 = ty.x;
            int lx2 = min(px0 + 2, 7), ly2 = min(py0 + 2, 7);
            const char* r0 = pb + (py0*8 + px0)*512;
            const char* r1 = pb + (min(py0+1,7)*8 + px0)*512;
            const char* r2 = pb + (ly2*8 + px0)*512;
            int dx2 = (lx2 - px0)*512;
            u32x2 F00 = *(const u32x2*)(r0);
            u32x2 F01 = *(const u32x2*)(r0 + 512);
            u32x2 F02 = *(const u32x2*)(r0 + dx2);
            u32x2 F10 = *(const u32x2*)(r1);
            u32x2 F11 = *(const u32x2*)(r1 + 512);
            u32x2 F12 = *(const u32x2*)(r1 + dx2);
            u32x2 F20 = *(const u32x2*)(r2);
            u32x2 F21 = *(const u32x2*)(r2 + 512);
            u32x2 F22 = *(const u32x2*)(r2 + dx2);
            __half2 xa = asH2(tx.y), xb2 = asH2(tx.z), xc = asH2(tx.w);
            __half2 ya = asH2(ty.y), yb2 = asH2(ty.z), yc = asH2(ty.w);
            u32x2 res;
#pragma unroll
            for (int s = 0; s < 2; ++s) {
                __half2 q0 = __hfma2(asH2(F02[s]), xc, __hfma2(asH2(F01[s]), xb2, __hmul2(asH2(F00[s]), xa)));
                __half2 q1 = __hfma2(asH2(F12[s]), xc, __hfma2(asH2(F11[s]), xb2, __hmul2(asH2(F10[s]), xa)));
                __half2 q2 = __hfma2(asH2(F22[s]), xc, __hfma2(asH2(F21[s]), xb2, __hmul2(asH2(F20[s]), xa)));
                res[s] = asU32(__hfma2(q2, yc, __hfma2(q1, yb2, __hmul2(q0, ya))));
            }
            *(u32x2*)(Pl[buf] + e*512 + ((cq*8) ^ ((e & 7) << 4))) = res;
        }
    };

    // ---- GEMM step j: acc += W(j, ot) x Pl[j&1] ----
    auto gemm = [&](int j) {
        int buf = j & 1;
        int ot = oh*4 + wid;
        const f16x8* wb = (const f16x8*)wr + (size_t)((j*8 + ot)*16)*64 + lane;
#pragma unroll
        for (int sk = 0; sk < 16; ++sk) {
            f16x8 wfrag = wb[sk*64];
            int byo = r31*512 + ((sk*32 + l5*16) ^ ((r31 & 7) << 4));
            f16x8 pf = *(const f16x8*)(Pl[buf] + byo);
            acc = __builtin_amdgcn_mfma_f32_32x32x16_f16(wfrag, pf, acc, 0, 0, 0);
        }
    };

    // prologue
    tables(0);
    __syncthreads();
    patchStage(0);
    tables(1);
    __syncthreads();       // drains gload_lds (vmcnt) + makes tabs[1] visible
    pool(0);
    __syncthreads();

    for (int j = 0; j < 8; ++j) {
        if (j < 7) patchStage(j+1);
        gemm(j);
        __syncthreads();
        if (j < 7) {
            pool(j+1);
            if (j < 6) tables(j+2);
            __syncthreads();
        }
    }

    // ---- epilogue: bias + relu ----
    int hw = hh*32 + r31;
    if (hw < 49) {
        int ot = oh*4 + wid;
        float* ob = out + (size_t)n*12544 + hw;
#pragma unroll
        for (int reg = 0; reg < 16; ++reg) {
            int o = ot*32 + (reg & 3) + 8*(reg >> 2) + 4*l5;
            float v = acc[reg] + bfuse[o];
            ob[(size_t)o*49] = fmaxf(v, 0.f);
        }
    }
}

extern "C" void kernel_launch(void* const* d_in, const int* in_sizes, int n_in,
                              void* d_out, int out_size, void* d_ws, size_t ws_size,
                              hipStream_t stream) {
    const float* feat  = (const float*)d_in[0];   // [256,64,64]
    const float* boxes = (const float*)d_in[1];   // [128,4]
    const float* wf    = (const float*)d_in[2];   // [256,2048]
    const float* bfuse = (const float*)d_in[3];   // [256]
    float* out = (float*)d_out;                   // [128,256,7,7]

    char* ws = (char*)d_ws;
    __half* wr    = (__half*)ws;                  // 1 MB (permuted W, fp16)
    __half* featT = (__half*)(ws + (1u<<20));     // 2 MB (fp16 feat, pix-major)

    k_transpose<<<256, 256, 0, stream>>>(feat, featT);
    k_permw<<<256, 256, 0, stream>>>(wf, wr);
    k_fused<<<512, 256, 0, stream>>>(featT, boxes, wr, bfuse, out);
}

// Round 11
// 39.740 us; speedup vs baseline: 1.5286x; 1.1869x over previous
//
#include <hip/hip_runtime.h>
#include <hip/hip_fp16.h>

#define SCALE (1.0f/16.0f)

typedef __attribute__((ext_vector_type(8))) _Float16 f16x8;
typedef __attribute__((ext_vector_type(4))) float f32x4;
typedef __attribute__((ext_vector_type(16))) float f32x16;
typedef __attribute__((ext_vector_type(4))) unsigned int u32x4;
typedef unsigned int u32;

__device__ __forceinline__ void gload16(const void* g, void* l) {
    __builtin_amdgcn_global_load_lds(
        (const __attribute__((address_space(1))) unsigned int*)g,
        (__attribute__((address_space(3))) unsigned int*)l, 16, 0, 0);
}
__device__ __forceinline__ __half2 asH2(u32 v) {
    union { u32 i; __half2 h; } u; u.i = v; return u.h;
}
__device__ __forceinline__ u32 asU32(__half2 h) {
    union { __half2 h; u32 i; } u; u.h = h; return u.i;
}
__device__ __forceinline__ int dupH2(float f) {
    __half h = __float2half_rn(f);
    __half2 d; d.x = h; d.y = h;
    union { __half2 h2; int i; } u; u.h2 = d; return u.i;
}

// ---------------- K1: prep = transpose (blocks 0..255) + permw (blocks 256..511) ----------------
// transpose: feat f32 [256 c][4096 pix] -> featT fp16 [4096 pix][256 c]
// permw: W f32 [256 o][2048 k] -> fp16 MFMA A-frag order:
//   chunk ch = ((j*8 + ot)*16 + sk)*64 + l : 8 fp16 of W[o=ot*32+(l&31)][k=j*256+sk*16+(l>>5)*8+i]
__global__ void k_prep(const float* __restrict__ feat, __half* __restrict__ featT,
                       const float* __restrict__ wf, __half* __restrict__ wr) {
    __shared__ float t[64][65];
    int b = blockIdx.x;
    if (b < 256) {
        int cb = (b >> 6) << 6;
        int pb = (b & 63) << 6;
        int lx = threadIdx.x & 63, ly = threadIdx.x >> 6;
#pragma unroll
        for (int i = 0; i < 16; ++i) {
            int cl = i*4 + ly;
            t[cl][lx] = feat[(size_t)(cb + cl) * 4096 + pb + lx];
        }
        __syncthreads();
#pragma unroll
        for (int i = 0; i < 16; ++i) {
            int pl = i*4 + ly;
            featT[(size_t)(pb + pl) * 256 + cb + lx] = __float2half_rn(t[lx][pl]);
        }
    } else {
        int ch = (b - 256) * 256 + threadIdx.x;   // 65536 chunks
        int l  = ch & 63;
        int sk = (ch >> 6) & 15;
        int ot = (ch >> 10) & 7;
        int j  = ch >> 13;
        int o = ot*32 + (l & 31);
        int k = j*256 + sk*16 + (l >> 5)*8;
        const float* src = wf + (size_t)o*2048 + k;
        f32x4 a = *(const f32x4*)src;
        f32x4 bb = *(const f32x4*)(src + 4);
        f16x8 p;
#pragma unroll
        for (int u = 0; u < 4; ++u) p[u] = (_Float16)a[u];
#pragma unroll
        for (int u = 0; u < 4; ++u) p[4+u] = (_Float16)bb[u];
        *((f16x8*)wr + ch) = p;
    }
}

// ---------------- K2: fused ROIAlign + GEMM, 512-thr blocks, 4 waves/SIMD ----------------
// Grid 256: (n 0..127, hh 0..1). 8 waves; wave wid = o-tile (32 o) x 32 hw.
// Per j: A:{gemm(j) || gload patch(j+1)} bar B:{pool(j+1) || tables(j+2)} bar.
__global__ void __launch_bounds__(512, 4) k_fused(
    const __half* __restrict__ featT,
    const float* __restrict__ boxes,
    const __half* __restrict__ wr,
    const float* __restrict__ bfuse,
    float* __restrict__ out)
{
    __shared__ char patch[32768];        // [y 8][px 8][c 256] fp16 (row = 4KB contiguous)
    __shared__ char Pl[2][16384];        // [32 hw][256 c] fp16, XOR-swizzled 16B slots
    __shared__ int4 tabs[2][2][7];       // [buf][x/y][idx] = {p0_local, a0h2, a1h2, a2h2}
    __shared__ int  pbs[2][2];           // [buf][xb, yb]

    int tid = threadIdx.x;
    int lane = tid & 63, wid = tid >> 6;     // 8 waves
    int r31 = lane & 31, l5 = lane >> 5;
    int bid = blockIdx.x;
    int n  = bid & 127;
    int hh = bid >> 7;
    int HWn = hh ? 17 : 32;

    int nb_base = (n & 15) * 8;
    int off = n >> 4;
    int t3 = off + (off >= 4 ? 1 : 0);
    int ci = t3 / 3, cj = t3 - ci*3;

    f32x16 acc;
#pragma unroll
    for (int i = 0; i < 16; ++i) acc[i] = 0.f;

    // ---- 3-tap separable tables + patch base for box jj (waves 0,1) ----
    auto tables = [&](int jj) {
        if (wid < 2) {
            int isy = wid;
            int nbx = nb_base + jj;
            float bx1 = boxes[nbx*4+0], by1 = boxes[nbx*4+1];
            float bx2 = boxes[nbx*4+2], by2 = boxes[nbx*4+3];
            float w3 = (bx2-bx1)*(1.f/3.f), h3 = (by2-by1)*(1.f/3.f);
            float org  = isy ? (by1 + ci*h3)*SCALE - 0.5f : (bx1 + cj*w3)*SCALE - 0.5f;
            float step = (isy ? h3 : w3) * (SCALE*(1.f/14.f));   // half-bin
            float sc = isy ? 0.25f : 1.f;
            float p = org + ((float)lane + 0.5f)*step;
            float pc = fminf(fmaxf(p, 0.f), 63.f);
            float fl = fminf(floorf(pc), 62.f);
            float fr = pc - fl;
            float c0 = __shfl(fl, 2*lane);
            float c1 = __shfl(fl, 2*lane+1);
            float f  = __shfl(fr, 2*lane);
            float f2 = __shfl(fr, 2*lane+1);
            float fl0 = __shfl(fl, 0);
            int base = min((int)fl0, 56);
            float d = c1 - c0;             // 0 or 1
            float a0 = sc*((1.f-f) + (1.f-d)*(1.f-f2));
            float a1 = sc*(f + (1.f-d)*f2 + d*(1.f-f2));
            float a2 = sc*(d*f2);
            if (lane < 7) {
                int4 e;
                e.x = (int)c0 - base;
                e.y = dupH2(a0); e.z = dupH2(a1); e.w = dupH2(a2);
                tabs[jj & 1][isy][lane] = e;
            }
            if (lane == 0) pbs[jj & 1][isy] = base;
        }
    };

    // ---- stage 8x8 px patch of box jj: wave wid stages row wid (4KB contiguous) ----
    auto patchStage = [&](int jj) {
        int xb = pbs[jj & 1][0], yb = pbs[jj & 1][1];
        const __half* src = featT + ((size_t)((yb + wid)*64 + xb))*256 + lane*8;
        char* dst = patch + wid*4096;
#pragma unroll
        for (int seg = 0; seg < 4; ++seg)
            gload16(src + seg*512, dst + seg*1024);
    };

    // ---- pool box jj from LDS patch (fp16 packed 9-tap separable) -> Pl[jj&1] ----
    auto pool = [&](int jj) {
        int buf = jj & 1;
        int co = tid & 31;          // c-octet 0..31 (8 channels = 16B)
        int e0 = tid >> 5;          // 0..15
        const char* pb = patch + co*16;
        for (int e = e0; e < HWn; e += 16) {
            int g = hh*32 + e;
            int h = (g*37) >> 8, w = g - h*7;
            int4 tx = tabs[buf][0][w], ty = tabs[buf][1][h];
            int px0 = tx.x, py0 = ty.x;
            int lx2 = min(px0 + 2, 7), ly2 = min(py0 + 2, 7);
            const char* r0 = pb + (py0*8 + px0)*512;
            const char* r1 = pb + (min(py0+1,7)*8 + px0)*512;
            const char* r2 = pb + (ly2*8 + px0)*512;
            int dx2 = (lx2 - px0)*512;
            u32x4 F00 = *(const u32x4*)(r0);
            u32x4 F01 = *(const u32x4*)(r0 + 512);
            u32x4 F02 = *(const u32x4*)(r0 + dx2);
            u32x4 F10 = *(const u32x4*)(r1);
            u32x4 F11 = *(const u32x4*)(r1 + 512);
            u32x4 F12 = *(const u32x4*)(r1 + dx2);
            u32x4 F20 = *(const u32x4*)(r2);
            u32x4 F21 = *(const u32x4*)(r2 + 512);
            u32x4 F22 = *(const u32x4*)(r2 + dx2);
            __half2 xa = asH2(tx.y), xb2 = asH2(tx.z), xc = asH2(tx.w);
            __half2 ya = asH2(ty.y), yb2 = asH2(ty.z), yc = asH2(ty.w);
            u32x4 res;
#pragma unroll
            for (int s = 0; s < 4; ++s) {
                __half2 q0 = __hfma2(asH2(F02[s]), xc, __hfma2(asH2(F01[s]), xb2, __hmul2(asH2(F00[s]), xa)));
                __half2 q1 = __hfma2(asH2(F12[s]), xc, __hfma2(asH2(F11[s]), xb2, __hmul2(asH2(F10[s]), xa)));
                __half2 q2 = __hfma2(asH2(F22[s]), xc, __hfma2(asH2(F21[s]), xb2, __hmul2(asH2(F20[s]), xa)));
                res[s] = asU32(__hfma2(q2, yc, __hfma2(q1, yb2, __hmul2(q0, ya))));
            }
            *(u32x4*)(Pl[buf] + e*512 + ((co*16) ^ ((e & 7) << 4))) = res;
        }
    };

    // ---- GEMM step j: acc += W(j, wid) x Pl[j&1], two 8-frag halves (VGPR<128) ----
    auto gemm = [&](int j) {
        int buf = j & 1;
        const f16x8* wb = (const f16x8*)wr + (size_t)((j*8 + wid)*16)*64 + lane;
#pragma unroll
        for (int half = 0; half < 2; ++half) {
            f16x8 wfr[8];
#pragma unroll
            for (int s = 0; s < 8; ++s) wfr[s] = wb[(half*8 + s)*64];
#pragma unroll
            for (int s = 0; s < 8; ++s) {
                int sk = half*8 + s;
                int byo = r31*512 + ((sk*32 + l5*16) ^ ((r31 & 7) << 4));
                f16x8 pf = *(const f16x8*)(Pl[buf] + byo);
                acc = __builtin_amdgcn_mfma_f32_32x32x16_f16(wfr[s], pf, acc, 0, 0, 0);
            }
        }
    };

    // prologue
    tables(0);
    __syncthreads();
    patchStage(0);
    tables(1);
    __syncthreads();       // drains gload_lds + makes tabs visible
    pool(0);
    __syncthreads();

    for (int j = 0; j < 8; ++j) {
        if (j < 7) patchStage(j+1);
        gemm(j);
        __syncthreads();
        if (j < 7) {
            pool(j+1);
            if (j < 6) tables(j+2);
            __syncthreads();
        }
    }

    // ---- epilogue: bias + relu ----
    int hw = hh*32 + r31;
    if (hw < 49) {
        float* ob = out + (size_t)n*12544 + hw;
#pragma unroll
        for (int reg = 0; reg < 16; ++reg) {
            int o = wid*32 + (reg & 3) + 8*(reg >> 2) + 4*l5;
            float v = acc[reg] + bfuse[o];
            ob[(size_t)o*49] = fmaxf(v, 0.f);
        }
    }
}

extern "C" void kernel_launch(void* const* d_in, const int* in_sizes, int n_in,
                              void* d_out, int out_size, void* d_ws, size_t ws_size,
                              hipStream_t stream) {
    const float* feat  = (const float*)d_in[0];   // [256,64,64]
    const float* boxes = (const float*)d_in[1];   // [128,4]
    const float* wf    = (const float*)d_in[2];   // [256,2048]
    const float* bfuse = (const float*)d_in[3];   // [256]
    float* out = (float*)d_out;                   // [128,256,7,7]

    char* ws = (char*)d_ws;
    __half* wr    = (__half*)ws;                  // 1 MB (permuted W, fp16)
    __half* featT = (__half*)(ws + (1u<<20));     // 2 MB (fp16 feat, pix-major)

    k_prep<<<512, 256, 0, stream>>>(feat, featT, wf, wr);
    k_fused<<<256, 512, 0, stream>>>(featT, boxes, wr, bfuse, out);
}

// Round 12
// 30.910 us; speedup vs baseline: 1.9653x; 1.2857x over previous
//
#include <hip/hip_runtime.h>
#include <hip/hip_fp16.h>

#define SCALE (1.0f/16.0f)

typedef __attribute__((ext_vector_type(8))) _Float16 f16x8;
typedef __attribute__((ext_vector_type(4))) float f32x4;
typedef __attribute__((ext_vector_type(16))) float f32x16;
typedef __attribute__((ext_vector_type(4))) unsigned int u32x4;
typedef unsigned int u32;

__device__ __forceinline__ void gload16(const void* g, void* l) {
    __builtin_amdgcn_global_load_lds(
        (const __attribute__((address_space(1))) unsigned int*)g,
        (__attribute__((address_space(3))) unsigned int*)l, 16, 0, 0);
}
__device__ __forceinline__ __half2 asH2(u32 v) {
    union { u32 i; __half2 h; } u; u.i = v; return u.h;
}
__device__ __forceinline__ u32 asU32(__half2 h) {
    union { __half2 h; u32 i; } u; u.h = h; return u.i;
}
__device__ __forceinline__ int dupH2(float f) {
    __half h = __float2half_rn(f);
    __half2 d; d.x = h; d.y = h;
    union { __half2 h2; int i; } u; u.h2 = d; return u.i;
}

// ---------------- K1: prep = transpose (blocks 0..255) + permw (blocks 256..511) ----------------
__global__ void k_prep(const float* __restrict__ feat, __half* __restrict__ featT,
                       const float* __restrict__ wf, __half* __restrict__ wr) {
    __shared__ float t[64][65];
    int b = blockIdx.x;
    if (b < 256) {
        int cb = (b >> 6) << 6;
        int pb = (b & 63) << 6;
        int lx = threadIdx.x & 63, ly = threadIdx.x >> 6;
#pragma unroll
        for (int i = 0; i < 16; ++i) {
            int cl = i*4 + ly;
            t[cl][lx] = feat[(size_t)(cb + cl) * 4096 + pb + lx];
        }
        __syncthreads();
#pragma unroll
        for (int i = 0; i < 16; ++i) {
            int pl = i*4 + ly;
            featT[(size_t)(pb + pl) * 256 + cb + lx] = __float2half_rn(t[lx][pl]);
        }
    } else {
        int ch = (b - 256) * 256 + threadIdx.x;   // 65536 chunks
        int l  = ch & 63;
        int sk = (ch >> 6) & 15;
        int ot = (ch >> 10) & 7;
        int j  = ch >> 13;
        int o = ot*32 + (l & 31);
        int k = j*256 + sk*16 + (l >> 5)*8;
        const float* src = wf + (size_t)o*2048 + k;
        f32x4 a = *(const f32x4*)src;
        f32x4 bb = *(const f32x4*)(src + 4);
        f16x8 p;
#pragma unroll
        for (int u = 0; u < 4; ++u) p[u] = (_Float16)a[u];
#pragma unroll
        for (int u = 0; u < 4; ++u) p[4+u] = (_Float16)bb[u];
        *((f16x8*)wr + ch) = p;
    }
}

// ---------------- K2: fused ROIAlign + GEMM, 4-deep pipeline, 1 barrier/j ----------------
// Grid 256: (n 0..127, hh 0..1). 512 thr = 8 waves; wave wid = o-tile (32 o) x 32 hw.
__global__ void __launch_bounds__(512, 2) k_fused(
    const __half* __restrict__ featT,
    const float* __restrict__ boxes,
    const __half* __restrict__ wr,
    const float* __restrict__ bfuse,
    float* __restrict__ out)
{
    __shared__ char patch[2][32768];     // [buf][y 8][px 8][c 256] fp16
    __shared__ char Pl[2][16384];        // [buf][32 hw][256 c] fp16, XOR-swizzled
    __shared__ int4 tabs[4][2][7];       // [box&3][x/y][idx] = {p0_local, a0h2, a1h2, a2h2}
    __shared__ int  pbs[4][2];           // [box&3][xb, yb]

    int tid = threadIdx.x;
    int lane = tid & 63, wid = tid >> 6;     // 8 waves
    int r31 = lane & 31, l5 = lane >> 5;
    int bid = blockIdx.x;
    int n  = bid & 127;
    int hh = bid >> 7;
    int HWn = hh ? 17 : 32;

    int nb_base = (n & 15) * 8;
    int off = n >> 4;
    int t3 = off + (off >= 4 ? 1 : 0);
    int ci = t3 / 3, cj = t3 - ci*3;

    f32x16 acc;
#pragma unroll
    for (int i = 0; i < 16; ++i) acc[i] = 0.f;

    // ---- 3-tap table builder for (box jj) on a given wave-pair role ----
    auto tablesW = [&](int jj, int isy, bool active) {
        if (active) {
            int nbx = nb_base + jj;
            float bx1 = boxes[nbx*4+0], by1 = boxes[nbx*4+1];
            float bx2 = boxes[nbx*4+2], by2 = boxes[nbx*4+3];
            float w3 = (bx2-bx1)*(1.f/3.f), h3 = (by2-by1)*(1.f/3.f);
            float org  = isy ? (by1 + ci*h3)*SCALE - 0.5f : (bx1 + cj*w3)*SCALE - 0.5f;
            float step = (isy ? h3 : w3) * (SCALE*(1.f/14.f));
            float sc = isy ? 0.25f : 1.f;
            float p = org + ((float)lane + 0.5f)*step;
            float pc = fminf(fmaxf(p, 0.f), 63.f);
            float fl = fminf(floorf(pc), 62.f);
            float fr = pc - fl;
            float c0 = __shfl(fl, 2*lane);
            float c1 = __shfl(fl, 2*lane+1);
            float f  = __shfl(fr, 2*lane);
            float f2 = __shfl(fr, 2*lane+1);
            float fl0 = __shfl(fl, 0);
            int base = min((int)fl0, 56);
            float d = c1 - c0;
            float a0 = sc*((1.f-f) + (1.f-d)*(1.f-f2));
            float a1 = sc*(f + (1.f-d)*f2 + d*(1.f-f2));
            float a2 = sc*(d*f2);
            if (lane < 7) {
                int4 e;
                e.x = (int)c0 - base;
                e.y = dupH2(a0); e.z = dupH2(a1); e.w = dupH2(a2);
                tabs[jj & 3][isy][lane] = e;
            }
            if (lane == 0) pbs[jj & 3][isy] = base;
        }
    };

    // ---- stage 8x8 px patch of box jj into patch[jj&1] ----
    auto patchStage = [&](int jj) {
        int xb = pbs[jj & 3][0], yb = pbs[jj & 3][1];
        const __half* src = featT + ((size_t)((yb + wid)*64 + xb))*256 + lane*8;
        char* dst = patch[jj & 1] + wid*4096;
#pragma unroll
        for (int seg = 0; seg < 4; ++seg)
            gload16(src + seg*512, dst + seg*1024);
    };

    // ---- pool box jj from patch[jj&1] -> Pl[jj&1] ----
    auto pool = [&](int jj) {
        int buf = jj & 1;
        int co = tid & 31;
        int e0 = tid >> 5;
        const char* pb = patch[buf] + co*16;
        for (int e = e0; e < HWn; e += 16) {
            int g = hh*32 + e;
            int h = (g*37) >> 8, w = g - h*7;
            int4 tx = tabs[jj & 3][0][w], ty = tabs[jj & 3][1][h];
            int px0 = tx.x, py0 = ty.x;
            int lx2 = min(px0 + 2, 7), ly2 = min(py0 + 2, 7);
            const char* r0 = pb + (py0*8 + px0)*512;
            const char* r1 = pb + (min(py0+1,7)*8 + px0)*512;
            const char* r2 = pb + (ly2*8 + px0)*512;
            int dx2 = (lx2 - px0)*512;
            u32x4 F00 = *(const u32x4*)(r0);
            u32x4 F01 = *(const u32x4*)(r0 + 512);
            u32x4 F02 = *(const u32x4*)(r0 + dx2);
            u32x4 F10 = *(const u32x4*)(r1);
            u32x4 F11 = *(const u32x4*)(r1 + 512);
            u32x4 F12 = *(const u32x4*)(r1 + dx2);
            u32x4 F20 = *(const u32x4*)(r2);
            u32x4 F21 = *(const u32x4*)(r2 + 512);
            u32x4 F22 = *(const u32x4*)(r2 + dx2);
            __half2 xa = asH2(tx.y), xb2 = asH2(tx.z), xc = asH2(tx.w);
            __half2 ya = asH2(ty.y), yb2 = asH2(ty.z), yc = asH2(ty.w);
            u32x4 res;
#pragma unroll
            for (int s = 0; s < 4; ++s) {
                __half2 q0 = __hfma2(asH2(F02[s]), xc, __hfma2(asH2(F01[s]), xb2, __hmul2(asH2(F00[s]), xa)));
                __half2 q1 = __hfma2(asH2(F12[s]), xc, __hfma2(asH2(F11[s]), xb2, __hmul2(asH2(F10[s]), xa)));
                __half2 q2 = __hfma2(asH2(F22[s]), xc, __hfma2(asH2(F21[s]), xb2, __hmul2(asH2(F20[s]), xa)));
                res[s] = asU32(__hfma2(q2, yc, __hfma2(q1, yb2, __hmul2(q0, ya))));
            }
            *(u32x4*)(Pl[buf] + e*512 + ((co*16) ^ ((e & 7) << 4))) = res;
        }
    };

    // ---- W register double-buffer ----
    f16x8 Wf[2][16];
    auto prefW = [&](int j) {
        const f16x8* wb = (const f16x8*)wr + (size_t)((j*8 + wid)*16)*64 + lane;
#pragma unroll
        for (int sk = 0; sk < 16; ++sk) Wf[j & 1][sk] = wb[sk*64];
    };

    auto gemm = [&](int j) {
        int buf = j & 1;
#pragma unroll
        for (int sk = 0; sk < 16; ++sk) {
            int byo = r31*512 + ((sk*32 + l5*16) ^ ((r31 & 7) << 4));
            f16x8 pf = *(const f16x8*)(Pl[buf] + byo);
            acc = __builtin_amdgcn_mfma_f32_32x32x16_f16(Wf[j & 1][sk], pf, acc, 0, 0, 0);
        }
    };

    // ---- prologue: tables(0,1,2) by waves 0..5 ----
    tablesW(wid >> 1, wid & 1, wid < 6);
    __syncthreads();
    prefW(0);
    patchStage(0);
    patchStage(1);
    __syncthreads();       // drains gloads, tabs visible
    pool(0);
    __syncthreads();

#pragma unroll
    for (int j = 0; j < 8; ++j) {
        if (j < 7) prefW(j+1);
        if (j < 6) patchStage(j+2);
        gemm(j);
        if (j < 7) pool(j+1);
        if (j < 5) tablesW(j+3, wid, wid < 2);
        __syncthreads();
    }

    // ---- epilogue: bias + relu ----
    int hw = hh*32 + r31;
    if (hw < 49) {
        float* ob = out + (size_t)n*12544 + hw;
#pragma unroll
        for (int reg = 0; reg < 16; ++reg) {
            int o = wid*32 + (reg & 3) + 8*(reg >> 2) + 4*l5;
            float v = acc[reg] + bfuse[o];
            ob[(size_t)o*49] = fmaxf(v, 0.f);
        }
    }
}

extern "C" void kernel_launch(void* const* d_in, const int* in_sizes, int n_in,
                              void* d_out, int out_size, void* d_ws, size_t ws_size,
                              hipStream_t stream) {
    const float* feat  = (const float*)d_in[0];   // [256,64,64]
    const float* boxes = (const float*)d_in[1];   // [128,4]
    const float* wf    = (const float*)d_in[2];   // [256,2048]
    const float* bfuse = (const float*)d_in[3];   // [256]
    float* out = (float*)d_out;                   // [128,256,7,7]

    char* ws = (char*)d_ws;
    __half* wr    = (__half*)ws;                  // 1 MB (permuted W, fp16)
    __half* featT = (__half*)(ws + (1u<<20));     // 2 MB (fp16 feat, pix-major)

    k_prep<<<512, 256, 0, stream>>>(feat, featT, wf, wr);
    k_fused<<<256, 512, 0, stream>>>(featT, boxes, wr, bfuse, out);
}